// Round 4
// baseline (569.300 us; speedup 1.0000x reference)
//
#include <hip/hip_runtime.h>
#include <stdint.h>

// Bahdanau additive attention, MI355X (gfx950).
// B=32, T=2048, H=1024, U=1024. All inputs fp32; output context [B,H] fp32.
//
// R7 changes vs R6 (ONE lever):
//  - score_gemm K-loop software-pipelined (catalog T3 minimum-2-phase):
//    LDS double-buffer (2x32 KiB, still 2 blocks/CU), STAGE(kt+1) issued
//    BEFORE compute(kt), counted s_waitcnt vmcnt(8) (never 0 in-loop), raw
//    s_barrier (no vmcnt drain). R6's loop forced a vmcnt(0) drain between
//    stage and compute every K-step, exposing full L2 staging latency.
//    Fragment layout, epilogue, and all math unchanged.

#define B_ 32
#define T_ 2048
#define H_ 1024
#define U_ 1024
#define M_ (B_ * T_)

typedef __bf16 bf16x8 __attribute__((ext_vector_type(8)));
typedef float f32x4 __attribute__((ext_vector_type(4)));

__device__ __forceinline__ unsigned f2b(float f) {  // fp32 -> bf16 bits, RNE
  unsigned u = __float_as_uint(f);
  return (u + 0x7FFFu + ((u >> 16) & 1u)) >> 16;
}
__device__ __forceinline__ float b2f(unsigned short u) {
  return __uint_as_float(((unsigned)u) << 16);
}
__device__ __forceinline__ float fast_tanh(float x) {
  float xc = fminf(fmaxf(x, -12.f), 12.f);
  float t = exp2f(xc * 2.885390081777927f);  // 2*log2(e)
  return (t - 1.f) * __builtin_amdgcn_rcpf(t + 1.f);
}

#define AS1 __attribute__((address_space(1)))
#define AS3 __attribute__((address_space(3)))
__device__ __forceinline__ void gld_lds16(const void* g, void* l) {
  __builtin_amdgcn_global_load_lds((AS1 const void*)g, (AS3 void*)l, 16, 0, 0);
}

// Raw barrier: does NOT drain vmcnt (unlike __syncthreads). sched_barrier
// pins compiler motion across it.
__device__ __forceinline__ void BAR() {
  __builtin_amdgcn_sched_barrier(0);
  __builtin_amdgcn_s_barrier();
  __builtin_amdgcn_sched_barrier(0);
}

// ------------------------------------------------------------- prep
// Grid-partitioned fusion of four independent prologue tasks:
//   bx in [0,4096)     : conv_enc  (enc fp32 -> encA bf16 packed, LDS transpose)
//   bx in [4096,4608)  : conv_ua   (Ua fp32 -> Ub bf16 packed)
//   bx in [4608,5120)  : decproj   (dp4[hz][b][u] partials)
//   bx in [5120,5248)  : zero d_out (poisoned by harness; ctx_k atomicAdds)
__global__ __launch_bounds__(256) void prep_k(
    const float4* __restrict__ enc, uint4* __restrict__ outA,
    const float* __restrict__ Ua, uint4* __restrict__ Ub,
    const float* __restrict__ dh, const float* __restrict__ Wa,
    float* __restrict__ dp4, float* __restrict__ outz) {
  const int bx = blockIdx.x;
  const int tx = threadIdx.x;

  if (bx < 4096) {
    // ---- conv_enc: reads 16 rows (64 KB fp32), writes packed bf16.
    __shared__ uint4 L4[128 * 17];
    const int band = bx;
    const int mt = band >> 3;
    const int R = (band & 7) << 4;  // ml base within 128-row tile
    const float4* src = enc + (size_t)band * 4096;  // 16 rows * 256 float4
#pragma unroll
    for (int i = 0; i < 8; ++i) {
      int p = i * 256 + tx;  // pair index: row r, k8 chunk pc
      int r = p >> 7, pc = p & 127;
      float4 a = src[r * 256 + pc * 2];
      float4 b = src[r * 256 + pc * 2 + 1];
      uint4 o;
      o.x = f2b(a.x) | (f2b(a.y) << 16);
      o.y = f2b(a.z) | (f2b(a.w) << 16);
      o.z = f2b(b.x) | (f2b(b.y) << 16);
      o.w = f2b(b.z) | (f2b(b.w) << 16);
      L4[pc * 17 + r] = o;
    }
    __syncthreads();
    const int r2 = tx & 15, kq = (tx >> 4) & 3, w = tx >> 6;
#pragma unroll
    for (int j = 0; j < 8; ++j) {
      int k8 = j * 16 + w * 4 + kq;
      outA[((size_t)mt * 128 + k8) * 128 + R + r2] = L4[k8 * 17 + r2];
    }
  } else if (bx < 4608) {
    // ---- conv_ua: Ua [H][U] -> Ub [(H/8)][U][8] bf16, dense 16B writes.
    int id = (bx - 4096) * 256 + tx;  // 131072 = 128 h8 * 1024 u
    int h8 = id >> 10, u = id & 1023;
    const float* p = Ua + (size_t)(h8 << 3) * U_ + u;
    uint4 o;
    o.x = f2b(p[0]) | (f2b(p[U_]) << 16);
    o.y = f2b(p[2 * U_]) | (f2b(p[3 * U_]) << 16);
    o.z = f2b(p[4 * U_]) | (f2b(p[5 * U_]) << 16);
    o.w = f2b(p[6 * U_]) | (f2b(p[7 * U_]) << 16);
    Ub[(size_t)h8 * U_ + u] = o;
  } else if (bx < 5120) {
    // ---- decproj: dp4[hz][b][u] partial over 256-h chunk.
    int g = bx - 4608;  // 512 = 4 uc * 32 b * 4 hz
    const int u = (g & 3) * 256 + tx;
    const int b = (g >> 2) & 31, hz = g >> 7;
    const float* d = dh + b * H_ + hz * 256;
    const float* w = Wa + (size_t)(hz * 256) * U_ + u;
    float a0 = 0.f, a1 = 0.f, a2 = 0.f, a3 = 0.f;
#pragma unroll 4
    for (int h = 0; h < 256; h += 4) {
      a0 = fmaf(d[h + 0], w[(size_t)(h + 0) * U_], a0);
      a1 = fmaf(d[h + 1], w[(size_t)(h + 1) * U_], a1);
      a2 = fmaf(d[h + 2], w[(size_t)(h + 2) * U_], a2);
      a3 = fmaf(d[h + 3], w[(size_t)(h + 3) * U_], a3);
    }
    dp4[((hz * B_ + b) * U_) + u] = (a0 + a1) + (a2 + a3);
  } else {
    // ---- zero d_out (32768 floats).
    outz[(bx - 5120) * 256 + tx] = 0.f;
  }
}

// ------------------------------------------------------------- fused GEMM
// 128^2 tile, double-buffered LDS, counted-vmcnt pipelined K-loop.
// Per K-step kt:
//   STAGE(kt+1 -> buf[nb])   (8 gld_lds16/thread; skipped at kt=15)
//   s_waitcnt vmcnt(8|0)     (tile kt's 8 loads done; kt+1's stay in flight)
//   BAR                      (collective: all waves' kt loads visible)
//   ds_read buf[cb] + 32 MFMA
//   BAR                      (all reads of cb done -> kt+2 may overwrite it)
// XCD swizzle: bx = (s<<6)|(m3<<3)|x -> mtile = s*8+x, ntile = m3; A-panel
// L2-resident across its 8 ntile-blocks.
__global__ __launch_bounds__(256, 2) void score_gemm_k(
    const unsigned short* __restrict__ encA,  // packed [mt][k8][ml][8]
    const unsigned short* __restrict__ Ub,    // [k8][N][8]
    const float* __restrict__ dp4,            // [4][B][U]
    const float* __restrict__ Va,             // [U]
    float* __restrict__ score8)               // [8][M]
{
  __shared__ union {
    struct {
      alignas(16) unsigned short As[2][8][128][8];  // [buf][k8][m][j] 32 KiB
      alignas(16) unsigned short Bs[2][8][128][8];  // [buf][k8][n][j] 32 KiB
    } t;
    float sred[128 * 33];  // epilogue scratch, stride-33 pad
  } sm;

  const int bx = blockIdx.x;
  const int mtile = ((bx >> 6) << 3) | (bx & 7), ntile = (bx >> 3) & 7;
  const int m0 = mtile << 7, n0 = ntile << 7;
  const int tid = threadIdx.x;
  const int wv = tid >> 6, ln = tid & 63;
  const int wm = wv & 1, wn = wv >> 1;
  const int quad = ln >> 4, l16 = ln & 15;

  f32x4 acc[4][4];
  const f32x4 zero = {0.f, 0.f, 0.f, 0.f};
#pragma unroll
  for (int i = 0; i < 4; ++i)
#pragma unroll
    for (int j = 0; j < 4; ++j) acc[i][j] = zero;

  const unsigned short* encT = encA + (size_t)mtile * (128 * 128 * 8);

  // Stage K-tile kt (BK=64 = 8 k8-slots) into buffer bsel. 8 gld_lds16/thread.
  auto STAGE = [&](int kt, int bsel) {
    const int kb = kt << 3;
#pragma unroll
    for (int c = 0; c < 4; ++c) {
      int chunk = (wv << 2) + c;  // 0..15
      int k8 = chunk >> 1, half = (chunk & 1) << 6;
      const unsigned short* ga =
          encT + (((size_t)(kb + k8) * 128) + half + ln) * 8;
      gld_lds16(ga, &sm.t.As[bsel][k8][half][0]);
      const unsigned short* gb =
          Ub + (((size_t)(kb + k8) * U_) + n0 + half + ln) * 8;
      gld_lds16(gb, &sm.t.Bs[bsel][k8][half][0]);
    }
  };

  // Prologue: tile 0 -> buf 0.
  STAGE(0, 0);

  for (int kt = 0; kt < 16; ++kt) {
    const int cb = kt & 1, nb = cb ^ 1;
    if (kt < 15) {
      STAGE(kt + 1, nb);
      asm volatile("s_waitcnt vmcnt(8)" ::: "memory");
    } else {
      asm volatile("s_waitcnt vmcnt(0)" ::: "memory");
    }
    BAR();  // all waves' tile-kt stages complete -> LDS resident

#pragma unroll
    for (int kk = 0; kk < 2; ++kk) {
      int k8b = (kk << 2) + quad;
      bf16x8 af[4], bf[4];
#pragma unroll
      for (int mt = 0; mt < 4; ++mt)
        af[mt] =
            *(const bf16x8*)&sm.t.As[cb][k8b][(wm << 6) + (mt << 4) + l16][0];
#pragma unroll
      for (int nt = 0; nt < 4; ++nt)
        bf[nt] =
            *(const bf16x8*)&sm.t.Bs[cb][k8b][(wn << 6) + (nt << 4) + l16][0];
#pragma unroll
      for (int mt = 0; mt < 4; ++mt)
#pragma unroll
        for (int nt = 0; nt < 4; ++nt)
          acc[mt][nt] = __builtin_amdgcn_mfma_f32_16x16x32_bf16(
              af[mt], bf[nt], acc[mt][nt], 0, 0, 0);
    }
    BAR();  // all reads of buf[cb] done -> step kt+2 may overwrite it
  }

  // Epilogue: v = sum_nt tanh(acc + dp) * Va; LDS reduce over 32 col-groups.
  // C/D layout: col = l16, row = quad*4 + r.
  const int bq = m0 >> 11;  // batch (tile never straddles b)
  float va[4], dpv[4];
#pragma unroll
  for (int nt = 0; nt < 4; ++nt) {
    int col = n0 + (wn << 6) + (nt << 4) + l16;
    va[nt] = Va[col];
    dpv[nt] = dp4[bq * U_ + col] + dp4[B_ * U_ + bq * U_ + col] +
              dp4[2 * B_ * U_ + bq * U_ + col] + dp4[3 * B_ * U_ + bq * U_ + col];
  }
  __syncthreads();  // tile reads done everywhere; reuse LDS as sred
#pragma unroll
  for (int mt = 0; mt < 4; ++mt) {
#pragma unroll
    for (int r = 0; r < 4; ++r) {
      float v = 0.f;
#pragma unroll
      for (int nt = 0; nt < 4; ++nt)
        v += fast_tanh(acc[mt][nt][r] + dpv[nt]) * va[nt];
      int row = (wm << 6) + (mt << 4) + (quad << 2) + r;
      sm.sred[row * 33 + (wn << 4) + l16] = v;
    }
  }
  __syncthreads();
  if (tid < 128) {
    const float* p = &sm.sred[tid * 33];
    float s = 0.f;
#pragma unroll
    for (int j = 0; j < 32; ++j) s += p[j];
    score8[(size_t)ntile * M_ + m0 + tid] = s;
  }
}

// ------------------------------------------------------------- context
// Per (b, bt) block: recompute b's softmax from score8 (L2-resident, 32 KB
// reads), then accumulate this block's 128-t slice of context and atomicAdd
// into out[b][h] (zeroed by prep_k).
__global__ __launch_bounds__(256) void ctx_k(const uint4* __restrict__ encA,
                                             const float* __restrict__ score8,
                                             float* __restrict__ out) {
  const int b = blockIdx.y, bt = blockIdx.x, tid = threadIdx.x;
  __shared__ float s_sc[2048];   // summed scores for this b (8 KB)
  __shared__ float a_s[128];     // alpha slice for this bt
  __shared__ float red[4];
  __shared__ float cred[2][128][8];

  // 1) sum the 8 ntile slabs; keep in regs + LDS.
  float4 v0 = {0.f, 0.f, 0.f, 0.f}, v1 = {0.f, 0.f, 0.f, 0.f};
#pragma unroll
  for (int k = 0; k < 8; ++k) {
    const float4* p = (const float4*)(score8 + (size_t)k * M_ + b * T_);
    float4 x0 = p[tid * 2], x1 = p[tid * 2 + 1];
    v0.x += x0.x; v0.y += x0.y; v0.z += x0.z; v0.w += x0.w;
    v1.x += x1.x; v1.y += x1.y; v1.z += x1.z; v1.w += x1.w;
  }
  ((float4*)s_sc)[tid * 2] = v0;
  ((float4*)s_sc)[tid * 2 + 1] = v1;

  // 2) block max.
  float m = fmaxf(fmaxf(fmaxf(v0.x, v0.y), fmaxf(v0.z, v0.w)),
                  fmaxf(fmaxf(v1.x, v1.y), fmaxf(v1.z, v1.w)));
#pragma unroll
  for (int off = 32; off >= 1; off >>= 1) m = fmaxf(m, __shfl_xor(m, off));
  if ((tid & 63) == 0) red[tid >> 6] = m;
  __syncthreads();
  m = fmaxf(fmaxf(red[0], red[1]), fmaxf(red[2], red[3]));
  __syncthreads();

  // 3) block sum of exp.
  const float l2e = 1.4426950408889634f;
  float sum = exp2f((v0.x - m) * l2e) + exp2f((v0.y - m) * l2e) +
              exp2f((v0.z - m) * l2e) + exp2f((v0.w - m) * l2e) +
              exp2f((v1.x - m) * l2e) + exp2f((v1.y - m) * l2e) +
              exp2f((v1.z - m) * l2e) + exp2f((v1.w - m) * l2e);
#pragma unroll
  for (int off = 32; off >= 1; off >>= 1) sum += __shfl_xor(sum, off);
  if ((tid & 63) == 0) red[tid >> 6] = sum;
  __syncthreads();
  const float inv = 1.f / (red[0] + red[1] + red[2] + red[3]);

  // 4) alpha slice for this block's 128 t's.
  if (tid < 128) a_s[tid] = exp2f((s_sc[bt * 128 + tid] - m) * l2e) * inv;
  __syncthreads();

  // 5) context partial over this 128-t slice.
  const int tx = tid & 127, th = tid >> 7;
  const int mt = b * 16 + bt;
  const uint4* base = encA + ((size_t)mt * 128 + tx) * 128 + th * 64;
  float a[8];
#pragma unroll
  for (int j = 0; j < 8; ++j) a[j] = 0.f;
#pragma unroll 4
  for (int i = 0; i < 64; ++i) {
    float w = a_s[th * 64 + i];
    uint4 e = base[i];
    a[0] = fmaf(w, b2f((unsigned short)e.x), a[0]);
    a[1] = fmaf(w, b2f((unsigned short)(e.x >> 16)), a[1]);
    a[2] = fmaf(w, b2f((unsigned short)e.y), a[2]);
    a[3] = fmaf(w, b2f((unsigned short)(e.y >> 16)), a[3]);
    a[4] = fmaf(w, b2f((unsigned short)e.z), a[4]);
    a[5] = fmaf(w, b2f((unsigned short)(e.z >> 16)), a[5]);
    a[6] = fmaf(w, b2f((unsigned short)e.w), a[6]);
    a[7] = fmaf(w, b2f((unsigned short)(e.w >> 16)), a[7]);
  }
#pragma unroll
  for (int j = 0; j < 8; ++j) cred[th][tx][j] = a[j];
  __syncthreads();
  if (th == 0) {
    float* o = out + (size_t)b * H_ + tx * 8;
#pragma unroll
    for (int j = 0; j < 8; ++j)
      atomicAdd(&o[j], cred[0][tx][j] + cred[1][tx][j]);
  }
}

// ------------------------------------------------------------- launch
extern "C" void kernel_launch(void* const* d_in, const int* in_sizes, int n_in,
                              void* d_out, int out_size, void* d_ws, size_t ws_size,
                              hipStream_t stream) {
  const float* enc = (const float*)d_in[0];
  const float* dh  = (const float*)d_in[1];
  const float* Wa  = (const float*)d_in[2];
  const float* Ua  = (const float*)d_in[3];
  const float* Va  = (const float*)d_in[4];

  char* ws = (char*)d_ws;
  unsigned short* encA = (unsigned short*)ws;                     // 128 MiB
  unsigned short* Ub   = (unsigned short*)(ws + 134217728);       // 2 MiB
  float* dp4    = (float*)(ws + 136314880);                       // 512 KiB
  float* score8 = (float*)(ws + 136839168);                       // 2 MiB

  prep_k<<<5248, 256, 0, stream>>>((const float4*)enc, (uint4*)encA, Ua,
                                   (uint4*)Ub, dh, Wa, dp4, (float*)d_out);
  score_gemm_k<<<4096, 256, 0, stream>>>(encA, Ub, dp4, Va, score8);
  ctx_k<<<dim3(16, 32), 256, 0, stream>>>((const uint4*)encA, score8,
                                          (float*)d_out);
}

// Round 5
// 564.942 us; speedup vs baseline: 1.0077x; 1.0077x over previous
//
#include <hip/hip_runtime.h>
#include <stdint.h>

// Bahdanau additive attention, MI355X (gfx950).
// B=32, T=2048, H=1024, U=1024. All inputs fp32; output context [B,H] fp32.
//
// R8 changes vs R7 (ONE lever):
//  - score_gemm ported to the m201-style 8-phase 256^2 schedule: 8 waves
//    (2Mx4N, wave=128x64 out), BK=64 split into 2 k-halves (K=32 each =
//    one MFMA K-step), 4 phases/K-tile = (k-half, m-half). Per phase:
//    {8,4,8,4} ds_read_b128 (B-frags register-held across the m-half pair),
//    stage ONE 16-KiB unit with 6-phase lead, vmcnt(8) gates twice per
//    K-tile (never 0 until drain), raw s_barrier, setprio around MFMA.
//    LDS = 4 unit-slots x 2 parities = 128 KiB. Score written as 4 slabs.

#define B_ 32
#define T_ 2048
#define H_ 1024
#define U_ 1024
#define M_ (B_ * T_)

typedef __bf16 bf16x8 __attribute__((ext_vector_type(8)));
typedef float f32x4 __attribute__((ext_vector_type(4)));

__device__ __forceinline__ unsigned f2b(float f) {  // fp32 -> bf16 bits, RNE
  unsigned u = __float_as_uint(f);
  return (u + 0x7FFFu + ((u >> 16) & 1u)) >> 16;
}
__device__ __forceinline__ float b2f(unsigned short u) {
  return __uint_as_float(((unsigned)u) << 16);
}
__device__ __forceinline__ float fast_tanh(float x) {
  float xc = fminf(fmaxf(x, -12.f), 12.f);
  float t = exp2f(xc * 2.885390081777927f);  // 2*log2(e)
  return (t - 1.f) * __builtin_amdgcn_rcpf(t + 1.f);
}

#define AS1 __attribute__((address_space(1)))
#define AS3 __attribute__((address_space(3)))
__device__ __forceinline__ void gld_lds16(const void* g, void* l) {
  __builtin_amdgcn_global_load_lds((AS1 const void*)g, (AS3 void*)l, 16, 0, 0);
}

// Raw barrier: does NOT drain vmcnt. sched_barrier pins compiler motion.
__device__ __forceinline__ void BAR() {
  __builtin_amdgcn_sched_barrier(0);
  __builtin_amdgcn_s_barrier();
  __builtin_amdgcn_sched_barrier(0);
}

// ------------------------------------------------------------- prep
// Grid-partitioned fusion of four independent prologue tasks:
//   bx in [0,4096)     : conv_enc  (enc fp32 -> encA bf16 packed, LDS transpose)
//   bx in [4096,4608)  : conv_ua   (Ua fp32 -> Ub bf16 packed)
//   bx in [4608,5120)  : decproj   (dp4[hz][b][u] partials)
//   bx in [5120,5248)  : zero d_out (poisoned by harness; ctx_k atomicAdds)
__global__ __launch_bounds__(256) void prep_k(
    const float4* __restrict__ enc, uint4* __restrict__ outA,
    const float* __restrict__ Ua, uint4* __restrict__ Ub,
    const float* __restrict__ dh, const float* __restrict__ Wa,
    float* __restrict__ dp4, float* __restrict__ outz) {
  const int bx = blockIdx.x;
  const int tx = threadIdx.x;

  if (bx < 4096) {
    // ---- conv_enc: reads 16 rows (64 KB fp32), writes packed bf16.
    __shared__ uint4 L4[128 * 17];
    const int band = bx;
    const int mt = band >> 3;
    const int R = (band & 7) << 4;  // ml base within 128-row tile
    const float4* src = enc + (size_t)band * 4096;  // 16 rows * 256 float4
#pragma unroll
    for (int i = 0; i < 8; ++i) {
      int p = i * 256 + tx;  // pair index: row r, k8 chunk pc
      int r = p >> 7, pc = p & 127;
      float4 a = src[r * 256 + pc * 2];
      float4 b = src[r * 256 + pc * 2 + 1];
      uint4 o;
      o.x = f2b(a.x) | (f2b(a.y) << 16);
      o.y = f2b(a.z) | (f2b(a.w) << 16);
      o.z = f2b(b.x) | (f2b(b.y) << 16);
      o.w = f2b(b.z) | (f2b(b.w) << 16);
      L4[pc * 17 + r] = o;
    }
    __syncthreads();
    const int r2 = tx & 15, kq = (tx >> 4) & 3, w = tx >> 6;
#pragma unroll
    for (int j = 0; j < 8; ++j) {
      int k8 = j * 16 + w * 4 + kq;
      outA[((size_t)mt * 128 + k8) * 128 + R + r2] = L4[k8 * 17 + r2];
    }
  } else if (bx < 4608) {
    // ---- conv_ua: Ua [H][U] -> Ub [(H/8)][U][8] bf16, dense 16B writes.
    int id = (bx - 4096) * 256 + tx;  // 131072 = 128 h8 * 1024 u
    int h8 = id >> 10, u = id & 1023;
    const float* p = Ua + (size_t)(h8 << 3) * U_ + u;
    uint4 o;
    o.x = f2b(p[0]) | (f2b(p[U_]) << 16);
    o.y = f2b(p[2 * U_]) | (f2b(p[3 * U_]) << 16);
    o.z = f2b(p[4 * U_]) | (f2b(p[5 * U_]) << 16);
    o.w = f2b(p[6 * U_]) | (f2b(p[7 * U_]) << 16);
    Ub[(size_t)h8 * U_ + u] = o;
  } else if (bx < 5120) {
    // ---- decproj: dp4[hz][b][u] partial over 256-h chunk.
    int g = bx - 4608;  // 512 = 4 uc * 32 b * 4 hz
    const int u = (g & 3) * 256 + tx;
    const int b = (g >> 2) & 31, hz = g >> 7;
    const float* d = dh + b * H_ + hz * 256;
    const float* w = Wa + (size_t)(hz * 256) * U_ + u;
    float a0 = 0.f, a1 = 0.f, a2 = 0.f, a3 = 0.f;
#pragma unroll 4
    for (int h = 0; h < 256; h += 4) {
      a0 = fmaf(d[h + 0], w[(size_t)(h + 0) * U_], a0);
      a1 = fmaf(d[h + 1], w[(size_t)(h + 1) * U_], a1);
      a2 = fmaf(d[h + 2], w[(size_t)(h + 2) * U_], a2);
      a3 = fmaf(d[h + 3], w[(size_t)(h + 3) * U_], a3);
    }
    dp4[((hz * B_ + b) * U_) + u] = (a0 + a1) + (a2 + a3);
  } else {
    // ---- zero d_out (32768 floats).
    outz[(bx - 5120) * 256 + tx] = 0.f;
  }
}

// ------------------------------------------------------------- fused GEMM
// 256x256 tile, BK=64, 8 waves (2M x 4N), wave out = 128x64.
// K-tile kt = 4 phases q=(kk,mh): kk = k-half (K=32, one MFMA K-step),
// mh = m-half of the wave's 128 rows. Per phase:
//   ds_read: 4 A-frags (+4 B-frags at mh==0, register-held for mh==1)
//   stage unit n = 4*kt + q + 6  (6-phase lead; unit = {A,B}x{k0,k1},
//     16 KiB, 2 gld_lds16/thread, into parity slot (n>>2)&1)
//   vmcnt gate (q==1: 8|0, q==3: 8|4|-), s_barrier, setprio(1),
//   16 MFMA (acc[mh*4+fm][fn]), setprio(0), s_barrier.
// Ledger: units numbered n=4t+u, u={A.k0,B.k0,A.k1,B.k1}; vmcnt(8) leaves
// the 4 newest units (8 loads) in flight and certifies exactly the k-half
// needed 1 phase later. Write-after-read: each stage target's last reader
// finished >=1 barrier before the stage issues (per-unit check in R8 notes).
__global__ __launch_bounds__(512, 2) void score_gemm_k(
    const unsigned short* __restrict__ encA,  // packed [mt128][k8][ml][8]
    const unsigned short* __restrict__ Ub,    // [k8][N][8]
    const float* __restrict__ dp4,            // [4][B][U]
    const float* __restrict__ Va,             // [U]
    float* __restrict__ score4)               // [4][M]
{
  __shared__ union {
    struct {
      alignas(16) unsigned short As[2][2][4][256][8];  // [par][kk][k8l][row][8] 64K
      alignas(16) unsigned short Bs[2][2][4][256][8];  // [par][kk][k8l][col][8] 64K
    } t;
    float sred[256][4];  // epilogue scratch (4 KiB)
  } sm;

  // XCD swizzle: bx = g*8 + xcd; per XCD, consecutive g = 4 nt-blocks of one
  // mtile back-to-back -> 512 KiB A-panel L2-resident.
  const int bx = blockIdx.x;
  const int xcd = bx & 7, g = bx >> 3;
  const int mt2 = xcd * 32 + (g >> 2), nt2 = g & 3;
  const int n0 = nt2 << 8;
  const int tid = threadIdx.x;
  const int wv = tid >> 6, ln = tid & 63;
  const int wm = wv >> 2, wn = wv & 3;  // 2 x 4 wave grid
  const int quad = ln >> 4, l16 = ln & 15;

  // Stage unit u of K-tile t into parity slot t&1. 2 gld_lds16/thread.
  auto STAGE = [&](int t, int u) {
    const int par = t & 1;
    const int kk = u >> 1;
    const int k8base = t * 8 + kk * 4;
    if (!(u & 1)) {  // A: 256 rows x 4 k8 (16 KiB)
#pragma unroll
      for (int r = 0; r < 2; ++r) {
        int i = r * 512 + tid;  // 0..1023
        int k8l = i >> 8, row = i & 255;
        const unsigned short* ga =
            encA + (((size_t)(mt2 * 2 + (row >> 7)) * 128 + k8base + k8l) * 128 +
                    (row & 127)) * 8;
        gld_lds16(ga, &sm.t.As[par][kk][k8l][row][0]);
      }
    } else {  // B: 256 cols x 4 k8 (16 KiB)
#pragma unroll
      for (int r = 0; r < 2; ++r) {
        int i = r * 512 + tid;
        int k8l = i >> 8, col = i & 255;
        const unsigned short* gb =
            Ub + ((size_t)(k8base + k8l) * U_ + n0 + col) * 8;
        gld_lds16(gb, &sm.t.Bs[par][kk][k8l][col][0]);
      }
    }
  };

  f32x4 acc[8][4];
  const f32x4 zero = {0.f, 0.f, 0.f, 0.f};
#pragma unroll
  for (int i = 0; i < 8; ++i)
#pragma unroll
    for (int j = 0; j < 4; ++j) acc[i][j] = zero;

  // Prologue: units 0..5 (tile 0 complete + tile 1 k0-half), then certify
  // units 0,1 (tile 0 k-half 0): 12 loads out, vmcnt(8) retires oldest 4.
#pragma unroll
  for (int n = 0; n < 6; ++n) STAGE(n >> 2, n & 3);
  __builtin_amdgcn_sched_barrier(0);
  asm volatile("s_waitcnt vmcnt(8)" ::: "memory");
  __builtin_amdgcn_s_barrier();
  __builtin_amdgcn_sched_barrier(0);

  bf16x8 bfr[4];  // B frags, held across the (mh=0, mh=1) phase pair

#pragma unroll 2
  for (int kt = 0; kt < 16; ++kt) {
    const int par = kt & 1;
#pragma unroll
    for (int q = 0; q < 4; ++q) {
      const int kk = q >> 1, mh = q & 1;
      if (mh == 0) {
#pragma unroll
        for (int fn = 0; fn < 4; ++fn)
          bfr[fn] = *(const bf16x8*)&sm.t
                         .Bs[par][kk][quad][wn * 64 + fn * 16 + l16][0];
      }
      bf16x8 af[4];
#pragma unroll
      for (int fm = 0; fm < 4; ++fm)
        af[fm] = *(const bf16x8*)&sm.t
                      .As[par][kk][quad][wm * 128 + mh * 64 + fm * 16 + l16][0];
      {
        const int n = kt * 4 + q + 6;
        if (n < 64) STAGE(n >> 2, n & 3);
      }
      __builtin_amdgcn_sched_barrier(0);
      if (q == 1) {
        if (kt < 15)
          asm volatile("s_waitcnt vmcnt(8)" ::: "memory");
        else
          asm volatile("s_waitcnt vmcnt(0)" ::: "memory");
      } else if (q == 3) {
        if (kt < 14)
          asm volatile("s_waitcnt vmcnt(8)" ::: "memory");
        else if (kt == 14)
          asm volatile("s_waitcnt vmcnt(4)" ::: "memory");
      }
      __builtin_amdgcn_s_barrier();
      __builtin_amdgcn_sched_barrier(0);
      __builtin_amdgcn_s_setprio(1);
#pragma unroll
      for (int fm = 0; fm < 4; ++fm)
#pragma unroll
        for (int fn = 0; fn < 4; ++fn)
          acc[mh * 4 + fm][fn] = __builtin_amdgcn_mfma_f32_16x16x32_bf16(
              af[fm], bfr[fn], acc[mh * 4 + fm][fn], 0, 0, 0);
      __builtin_amdgcn_s_setprio(0);
      BAR();
    }
  }

  // ------------------------------------------------------ epilogue
  // v = sum_fn tanh(acc + dp) * Va; in-quad shfl reduce over l16 (16 cols),
  // cross-wn via 4 KiB sred. C/D: col = l16, row = quad*4 + rr.
  const int bq = mt2 >> 3;  // batch (256-row tile never straddles b)
  float va[4], dpv[4];
#pragma unroll
  for (int fn = 0; fn < 4; ++fn) {
    int col = n0 + wn * 64 + fn * 16 + l16;
    va[fn] = Va[col];
    dpv[fn] = dp4[bq * U_ + col] + dp4[B_ * U_ + bq * U_ + col] +
              dp4[2 * B_ * U_ + bq * U_ + col] +
              dp4[3 * B_ * U_ + bq * U_ + col];
  }
  __syncthreads();  // all tile reads/stages quiesced; reuse LDS as sred
#pragma unroll
  for (int i = 0; i < 8; ++i) {
#pragma unroll
    for (int rr = 0; rr < 4; ++rr) {
      float v = 0.f;
#pragma unroll
      for (int fn = 0; fn < 4; ++fn)
        v += fast_tanh(acc[i][fn][rr] + dpv[fn]) * va[fn];
#pragma unroll
      for (int off = 1; off < 16; off <<= 1) v += __shfl_xor(v, off);
      if (l16 == 0) sm.sred[wm * 128 + i * 16 + quad * 4 + rr][wn] = v;
    }
  }
  __syncthreads();
  if (tid < 256) {
    float s = sm.sred[tid][0] + sm.sred[tid][1] + sm.sred[tid][2] +
              sm.sred[tid][3];
    score4[(size_t)nt2 * M_ + mt2 * 256 + tid] = s;
  }
}

// ------------------------------------------------------------- context
// Per (b, bt) block: recompute b's softmax from score4 (L2-resident), then
// accumulate this block's 128-t slice of context and atomicAdd into
// out[b][h] (zeroed by prep_k).
__global__ __launch_bounds__(256) void ctx_k(const uint4* __restrict__ encA,
                                             const float* __restrict__ score4,
                                             float* __restrict__ out) {
  const int b = blockIdx.y, bt = blockIdx.x, tid = threadIdx.x;
  __shared__ float s_sc[2048];   // summed scores for this b (8 KB)
  __shared__ float a_s[128];     // alpha slice for this bt
  __shared__ float red[4];
  __shared__ float cred[2][128][8];

  // 1) sum the 4 ntile slabs; keep in regs + LDS.
  float4 v0 = {0.f, 0.f, 0.f, 0.f}, v1 = {0.f, 0.f, 0.f, 0.f};
#pragma unroll
  for (int k = 0; k < 4; ++k) {
    const float4* p = (const float4*)(score4 + (size_t)k * M_ + b * T_);
    float4 x0 = p[tid * 2], x1 = p[tid * 2 + 1];
    v0.x += x0.x; v0.y += x0.y; v0.z += x0.z; v0.w += x0.w;
    v1.x += x1.x; v1.y += x1.y; v1.z += x1.z; v1.w += x1.w;
  }
  ((float4*)s_sc)[tid * 2] = v0;
  ((float4*)s_sc)[tid * 2 + 1] = v1;

  // 2) block max.
  float m = fmaxf(fmaxf(fmaxf(v0.x, v0.y), fmaxf(v0.z, v0.w)),
                  fmaxf(fmaxf(v1.x, v1.y), fmaxf(v1.z, v1.w)));
#pragma unroll
  for (int off = 32; off >= 1; off >>= 1) m = fmaxf(m, __shfl_xor(m, off));
  if ((tid & 63) == 0) red[tid >> 6] = m;
  __syncthreads();
  m = fmaxf(fmaxf(red[0], red[1]), fmaxf(red[2], red[3]));
  __syncthreads();

  // 3) block sum of exp.
  const float l2e = 1.4426950408889634f;
  float sum = exp2f((v0.x - m) * l2e) + exp2f((v0.y - m) * l2e) +
              exp2f((v0.z - m) * l2e) + exp2f((v0.w - m) * l2e) +
              exp2f((v1.x - m) * l2e) + exp2f((v1.y - m) * l2e) +
              exp2f((v1.z - m) * l2e) + exp2f((v1.w - m) * l2e);
#pragma unroll
  for (int off = 32; off >= 1; off >>= 1) sum += __shfl_xor(sum, off);
  if ((tid & 63) == 0) red[tid >> 6] = sum;
  __syncthreads();
  const float inv = 1.f / (red[0] + red[1] + red[2] + red[3]);

  // 4) alpha slice for this block's 128 t's.
  if (tid < 128) a_s[tid] = exp2f((s_sc[bt * 128 + tid] - m) * l2e) * inv;
  __syncthreads();

  // 5) context partial over this 128-t slice.
  const int tx = tid & 127, th = tid >> 7;
  const int mt = b * 16 + bt;
  const uint4* base = encA + ((size_t)mt * 128 + tx) * 128 + th * 64;
  float a[8];
#pragma unroll
  for (int j = 0; j < 8; ++j) a[j] = 0.f;
#pragma unroll 4
  for (int i = 0; i < 64; ++i) {
    float w = a_s[th * 64 + i];
    uint4 e = base[i];
    a[0] = fmaf(w, b2f((unsigned short)e.x), a[0]);
    a[1] = fmaf(w, b2f((unsigned short)(e.x >> 16)), a[1]);
    a[2] = fmaf(w, b2f((unsigned short)e.y), a[2]);
    a[3] = fmaf(w, b2f((unsigned short)(e.y >> 16)), a[3]);
    a[4] = fmaf(w, b2f((unsigned short)e.z), a[4]);
    a[5] = fmaf(w, b2f((unsigned short)(e.z >> 16)), a[5]);
    a[6] = fmaf(w, b2f((unsigned short)e.w), a[6]);
    a[7] = fmaf(w, b2f((unsigned short)(e.w >> 16)), a[7]);
  }
#pragma unroll
  for (int j = 0; j < 8; ++j) cred[th][tx][j] = a[j];
  __syncthreads();
  if (th == 0) {
    float* o = out + (size_t)b * H_ + tx * 8;
#pragma unroll
    for (int j = 0; j < 8; ++j)
      atomicAdd(&o[j], cred[0][tx][j] + cred[1][tx][j]);
  }
}

// ------------------------------------------------------------- launch
extern "C" void kernel_launch(void* const* d_in, const int* in_sizes, int n_in,
                              void* d_out, int out_size, void* d_ws, size_t ws_size,
                              hipStream_t stream) {
  const float* enc = (const float*)d_in[0];
  const float* dh  = (const float*)d_in[1];
  const float* Wa  = (const float*)d_in[2];
  const float* Ua  = (const float*)d_in[3];
  const float* Va  = (const float*)d_in[4];

  char* ws = (char*)d_ws;
  unsigned short* encA = (unsigned short*)ws;                     // 128 MiB
  unsigned short* Ub   = (unsigned short*)(ws + 134217728);       // 2 MiB
  float* dp4    = (float*)(ws + 136314880);                       // 512 KiB
  float* score4 = (float*)(ws + 136839168);                       // 1 MiB

  prep_k<<<5248, 256, 0, stream>>>((const float4*)enc, (uint4*)encA, Ua,
                                   (uint4*)Ub, dh, Wa, dp4, (float*)d_out);
  score_gemm_k<<<1024, 512, 0, stream>>>(encA, Ub, dp4, Va, score4);
  ctx_k<<<dim3(16, 32), 256, 0, stream>>>((const uint4*)encA, score4,
                                          (float*)d_out);
}